// Round 1
// baseline (2218.088 us; speedup 1.0000x reference)
//
#include <hip/hip_runtime.h>
#include <hip/hip_bf16.h>

#define NN 100000
#define NE 600000
#define NR 500
#define DD 128
#define SLOPE 0.22916666666666666f

typedef __attribute__((ext_vector_type(4))) float f32x4;
typedef __attribute__((ext_vector_type(8))) short s16x8;
typedef __attribute__((ext_vector_type(4))) short s16x4;

__device__ __forceinline__ unsigned short f2b(float f) {
  union { float f; unsigned u; } v; v.f = f;
  unsigned u = v.u;
  return (unsigned short)((u + 0x7fffu + ((u >> 16) & 1u)) >> 16);
}

// Build Wt[L][c][k] (bf16), c = output col (0..127), k = input dim (0..255):
// k<128 -> W_rel[k][c] (multiplies pre*norm), k>=128 -> W_loop[k-128][c] (multiplies h).
__global__ void prep_w(const float* __restrict__ Wr0, const float* __restrict__ Wl0,
                       const float* __restrict__ Wr1, const float* __restrict__ Wl1,
                       unsigned short* __restrict__ Wt) {
  int idx = blockIdx.x * blockDim.x + threadIdx.x;
  if (idx >= 2 * 128 * 256) return;
  int L = idx >> 15;
  int rem = idx & 32767;
  int c = rem >> 8;
  int k = rem & 255;
  const float* Wr = L ? Wr1 : Wr0;
  const float* Wl = L ? Wl1 : Wl0;
  float v = (k < DD) ? Wr[k * DD + c] : Wl[(k - DD) * DD + c];
  Wt[idx] = f2b(v);
}

// pre[dst] += rel[rid] + h[src]; 32 threads (x float4) per edge.
__global__ void scatter_add(const float* __restrict__ h, const float* __restrict__ rel,
                            const int* __restrict__ src, const int* __restrict__ dst,
                            const int* __restrict__ rid, float* __restrict__ pre) {
  int gid = blockIdx.x * blockDim.x + threadIdx.x;
  int e = gid >> 5;
  if (e >= NE) return;
  int c = (gid & 31) << 2;
  int s = src[e], d = dst[e], r = rid[e];
  f32x4 hv = *(const f32x4*)(h + (size_t)s * DD + c);
  f32x4 rv = *(const f32x4*)(rel + (size_t)r * DD + c);
  float* p = pre + (size_t)d * DD + c;
  unsafeAtomicAdd(p + 0, hv[0] + rv[0]);
  unsafeAtomicAdd(p + 1, hv[1] + rv[1]);
  unsafeAtomicAdd(p + 2, hv[2] + rv[2]);
  unsafeAtomicAdd(p + 3, hv[3] + rv[3]);
}

// out = leaky_relu([pre*norm ; h] @ Wt^T-layout), 64-row tiles, bf16 MFMA 16x16x32.
// Safe to have out == h: each block only reads rows of its own tile (staged to LDS
// before any write), and blocks own disjoint row tiles.
__launch_bounds__(256)
__global__ void layer_mm(const float* __restrict__ pre, const float* __restrict__ h,
                         const float* __restrict__ norm, const unsigned short* __restrict__ Wt,
                         float* __restrict__ out) {
  // Bt[c][k] padded: stride 264 bf16 (528B = 33*16B -> 16B aligned rows, banks spread)
  __shared__ unsigned short Blds[128 * 264];
  __shared__ unsigned short Alds[64 * 264];
  int tid = threadIdx.x;
  int wave = tid >> 6, lane = tid & 63;
  int l16 = lane & 15, lhi = lane >> 4;

  // stage all of B (128 x 256 bf16) once per block
  for (int cc = tid; cc < 128 * 32; cc += 256) {
    int c = cc >> 5, kc = (cc & 31) << 3;
    *(s16x8*)(&Blds[c * 264 + kc]) = *(const s16x8*)(Wt + c * 256 + kc);
  }

  const int NT = (NN + 63) >> 6;
  for (int tile = blockIdx.x; tile < NT; tile += gridDim.x) {
    int row0 = tile << 6;
    __syncthreads();  // protect Alds reuse (and covers Blds staging on iter 0)
    // stage A: rows row0..row0+63, k 0..255 = [pre*norm (128) | h (128)] in bf16
    for (int cc = tid; cc < 64 * 64; cc += 256) {
      int m = cc >> 6, kc = (cc & 63) << 2;
      int gr = row0 + m;
      f32x4 v = {0.f, 0.f, 0.f, 0.f};
      if (gr < NN) {
        if (kc < DD) {
          v = *(const f32x4*)(pre + (size_t)gr * DD + kc);
          float nm = norm[gr];
          v[0] *= nm; v[1] *= nm; v[2] *= nm; v[3] *= nm;
        } else {
          v = *(const f32x4*)(h + (size_t)gr * DD + (kc - DD));
        }
      }
      s16x4 b;
      b[0] = (short)f2b(v[0]); b[1] = (short)f2b(v[1]);
      b[2] = (short)f2b(v[2]); b[3] = (short)f2b(v[3]);
      *(s16x4*)(&Alds[m * 264 + kc]) = b;
    }
    __syncthreads();

    // wave computes 16 rows x 128 cols; K = 256 in 8 steps of 32
    const unsigned short* Abase = &Alds[(wave * 16 + l16) * 264 + lhi * 8];
    s16x8 a[8];
#pragma unroll
    for (int k = 0; k < 8; k++) a[k] = *(const s16x8*)(Abase + k * 32);

    f32x4 acc[8];
#pragma unroll
    for (int n = 0; n < 8; n++) acc[n] = (f32x4){0.f, 0.f, 0.f, 0.f};
#pragma unroll
    for (int n = 0; n < 8; n++) {
      const unsigned short* Bb = &Blds[(n * 16 + l16) * 264 + lhi * 8];
#pragma unroll
      for (int k = 0; k < 8; k++) {
        s16x8 b = *(const s16x8*)(Bb + k * 32);
        acc[n] = __builtin_amdgcn_mfma_f32_16x16x32_bf16(a[k], b, acc[n], 0, 0, 0);
      }
    }

    // epilogue: leaky_relu, write fp32. D frag: row=(lane>>4)*4+j, col=lane&15
#pragma unroll
    for (int n = 0; n < 8; n++) {
#pragma unroll
      for (int j = 0; j < 4; j++) {
        int gr = row0 + wave * 16 + lhi * 4 + j;
        if (gr < NN) {
          float x = acc[n][j];
          out[(size_t)gr * DD + n * 16 + l16] = x > 0.f ? x : x * SLOPE;
        }
      }
    }
  }
}

extern "C" void kernel_launch(void* const* d_in, const int* in_sizes, int n_in,
                              void* d_out, int out_size, void* d_ws, size_t ws_size,
                              hipStream_t stream) {
  const float* ent  = (const float*)d_in[0];
  const float* rel  = (const float*)d_in[1];
  const float* norm = (const float*)d_in[2];
  const float* Wr0  = (const float*)d_in[3];
  const float* Wl0  = (const float*)d_in[4];
  const float* Wr1  = (const float*)d_in[5];
  const float* Wl1  = (const float*)d_in[6];
  const int* src = (const int*)d_in[7];
  const int* dst = (const int*)d_in[8];
  const int* rid = (const int*)d_in[9];
  float* out = (float*)d_out;

  char* ws = (char*)d_ws;
  float* pre = (float*)ws;                                        // NN*DD f32
  unsigned short* Wt = (unsigned short*)(ws + (size_t)NN * DD * 4); // 2*128*256 bf16

  prep_w<<<(2 * 128 * 256 + 255) / 256, 256, 0, stream>>>(Wr0, Wl0, Wr1, Wl1, Wt);

  const int scatter_blocks = (NE * 32 + 255) / 256;

  // layer 1
  hipMemsetAsync(pre, 0, (size_t)NN * DD * 4, stream);
  scatter_add<<<scatter_blocks, 256, 0, stream>>>(ent, rel, src, dst, rid, pre);
  layer_mm<<<256, 256, 0, stream>>>(pre, ent, norm, Wt, out);

  // layer 2 (reads out as h, writes out in place — per-tile safe)
  hipMemsetAsync(pre, 0, (size_t)NN * DD * 4, stream);
  scatter_add<<<scatter_blocks, 256, 0, stream>>>(out, rel, src, dst, rid, pre);
  layer_mm<<<256, 256, 0, stream>>>(pre, out, norm, Wt + 128 * 256, out);
}

// Round 2
// 273.732 us; speedup vs baseline: 8.1031x; 8.1031x over previous
//
#include <hip/hip_runtime.h>
#include <hip/hip_bf16.h>

#define NN 100000
#define NE 600000
#define DD 128
#define SLOPE 0.22916666666666666f
#define NB1 98  // ceil(NN/1024)

typedef __attribute__((ext_vector_type(4))) float f32x4;
typedef __attribute__((ext_vector_type(8))) short s16x8;
typedef __attribute__((ext_vector_type(4))) short s16x4;

__device__ __forceinline__ unsigned short f2b(float f) {
  union { float f; unsigned u; } v; v.f = f;
  unsigned u = v.u;
  return (unsigned short)((u + 0x7fffu + ((u >> 16) & 1u)) >> 16);
}

// Wt[L][c][k] bf16: k<128 -> W_rel[k][c], k>=128 -> W_loop[k-128][c]
__global__ void prep_w(const float* __restrict__ Wr0, const float* __restrict__ Wl0,
                       const float* __restrict__ Wr1, const float* __restrict__ Wl1,
                       unsigned short* __restrict__ Wt) {
  int idx = blockIdx.x * blockDim.x + threadIdx.x;
  if (idx >= 2 * 128 * 256) return;
  int L = idx >> 15;
  int rem = idx & 32767;
  int c = rem >> 8;
  int k = rem & 255;
  const float* Wr = L ? Wr1 : Wr0;
  const float* Wl = L ? Wl1 : Wl0;
  float v = (k < DD) ? Wr[k * DD + c] : Wl[(k - DD) * DD + c];
  Wt[idx] = f2b(v);
}

// ---------- CSR build (counting sort by dst) ----------
__global__ void hist_deg(const int* __restrict__ dst, int* __restrict__ deg) {
  int e = blockIdx.x * blockDim.x + threadIdx.x;
  if (e < NE) atomicAdd(&deg[dst[e]], 1);
}

// per-1024-chunk sums
__global__ void scan_a(const int* __restrict__ deg, int* __restrict__ psum) {
  __shared__ int lds[256];
  int b = blockIdx.x, t = threadIdx.x;
  int base = b * 1024 + t * 4;
  int s = 0;
#pragma unroll
  for (int j = 0; j < 4; j++) { int i = base + j; if (i < NN) s += deg[i]; }
  lds[t] = s; __syncthreads();
  for (int st = 128; st > 0; st >>= 1) { if (t < st) lds[t] += lds[t + st]; __syncthreads(); }
  if (t == 0) psum[b] = lds[0];
}

// exclusive scan of the NB1 chunk sums (single block, 128 threads)
__global__ void scan_b(int* __restrict__ psum) {
  __shared__ int lds[128];
  int t = threadIdx.x;
  lds[t] = (t < NB1) ? psum[t] : 0; __syncthreads();
  for (int st = 1; st < 128; st <<= 1) {
    int v = (t >= st) ? lds[t - st] : 0;
    __syncthreads();
    lds[t] += v;
    __syncthreads();
  }
  if (t < NB1) psum[t] = t ? lds[t - 1] : 0;
}

// final offsets: off[i] (and cur[i] copy for the fill pass)
__global__ void scan_c(const int* __restrict__ deg, const int* __restrict__ psum,
                       int* __restrict__ off, int* __restrict__ cur) {
  __shared__ int lds[256];
  int b = blockIdx.x, t = threadIdx.x;
  int base = b * 1024 + t * 4;
  int v[4]; int s = 0;
#pragma unroll
  for (int j = 0; j < 4; j++) { int i = base + j; v[j] = (i < NN) ? deg[i] : 0; s += v[j]; }
  lds[t] = s; __syncthreads();
  for (int st = 1; st < 256; st <<= 1) {
    int u = (t >= st) ? lds[t - st] : 0;
    __syncthreads();
    lds[t] += u;
    __syncthreads();
  }
  int run = (t ? lds[t - 1] : 0) + psum[b];
#pragma unroll
  for (int j = 0; j < 4; j++) {
    int i = base + j;
    if (i < NN) { off[i] = run; cur[i] = run; run += v[j]; }
  }
  if (b == 0 && t == 0) off[NN] = NE;
}

__global__ void fill_csr(const int* __restrict__ src, const int* __restrict__ dst,
                         const int* __restrict__ rid, int* __restrict__ cur,
                         int* __restrict__ esrc, int* __restrict__ erel) {
  int e = blockIdx.x * blockDim.x + threadIdx.x;
  if (e < NE) {
    int slot = atomicAdd(&cur[dst[e]], 1);
    esrc[slot] = src[e];
    erel[slot] = rid[e];
  }
}

// ---------- per-layer aggregation: gather over CSR, fold norm, emit bf16 ----------
__global__ void gather_csr(const float* __restrict__ h, const float* __restrict__ rel,
                           const float* __restrict__ norm, const int* __restrict__ off,
                           const int* __restrict__ esrc, const int* __restrict__ erel,
                           unsigned short* __restrict__ preb) {
  int gid = blockIdx.x * blockDim.x + threadIdx.x;
  int g = gid >> 5;
  if (g >= NN) return;
  int lane = (gid & 31) << 2;
  int beg = off[g], end = off[g + 1];
  float a0 = 0.f, a1 = 0.f, a2 = 0.f, a3 = 0.f;
  for (int e = beg; e < end; e++) {
    int s = esrc[e], r = erel[e];
    f32x4 hv = *(const f32x4*)(h + (size_t)s * DD + lane);
    f32x4 rv = *(const f32x4*)(rel + (size_t)r * DD + lane);
    a0 += hv[0] + rv[0]; a1 += hv[1] + rv[1];
    a2 += hv[2] + rv[2]; a3 += hv[3] + rv[3];
  }
  float nm = norm[g];
  s16x4 o;
  o[0] = (short)f2b(a0 * nm); o[1] = (short)f2b(a1 * nm);
  o[2] = (short)f2b(a2 * nm); o[3] = (short)f2b(a3 * nm);
  *(s16x4*)(preb + (size_t)g * DD + lane) = o;
}

// out = leaky_relu([preb ; bf16(h)] @ Wt), 64-row tiles, bf16 MFMA 16x16x32.
// out==h safe: blocks own disjoint row tiles; h rows staged to LDS before write.
__launch_bounds__(256)
__global__ void layer_mm(const unsigned short* __restrict__ preb, const float* __restrict__ h,
                         const unsigned short* __restrict__ Wt, float* __restrict__ out) {
  __shared__ unsigned short Blds[128 * 264];
  __shared__ unsigned short Alds[64 * 264];
  int tid = threadIdx.x;
  int wave = tid >> 6, lane = tid & 63;
  int l16 = lane & 15, lhi = lane >> 4;

  for (int cc = tid; cc < 128 * 32; cc += 256) {
    int c = cc >> 5, kc = (cc & 31) << 3;
    *(s16x8*)(&Blds[c * 264 + kc]) = *(const s16x8*)(Wt + c * 256 + kc);
  }

  const int NT = (NN + 63) >> 6;
  for (int tile = blockIdx.x; tile < NT; tile += gridDim.x) {
    int row0 = tile << 6;
    __syncthreads();
    // A k<128: aggregated bf16 rows (norm already folded)
    for (int cc = tid; cc < 64 * 16; cc += 256) {
      int m = cc >> 4, kc = (cc & 15) << 3;
      int gr = row0 + m;
      s16x8 v = {0, 0, 0, 0, 0, 0, 0, 0};
      if (gr < NN) v = *(const s16x8*)(preb + (size_t)gr * DD + kc);
      *(s16x8*)(&Alds[m * 264 + kc]) = v;
    }
    // A k>=128: h rows fp32 -> bf16
    for (int cc = tid; cc < 64 * 16; cc += 256) {
      int m = cc >> 4, kc = (cc & 15) << 3;
      int gr = row0 + m;
      s16x8 b = {0, 0, 0, 0, 0, 0, 0, 0};
      if (gr < NN) {
        f32x4 v0 = *(const f32x4*)(h + (size_t)gr * DD + kc);
        f32x4 v1 = *(const f32x4*)(h + (size_t)gr * DD + kc + 4);
        b[0] = (short)f2b(v0[0]); b[1] = (short)f2b(v0[1]);
        b[2] = (short)f2b(v0[2]); b[3] = (short)f2b(v0[3]);
        b[4] = (short)f2b(v1[0]); b[5] = (short)f2b(v1[1]);
        b[6] = (short)f2b(v1[2]); b[7] = (short)f2b(v1[3]);
      }
      *(s16x8*)(&Alds[m * 264 + 128 + kc]) = b;
    }
    __syncthreads();

    const unsigned short* Abase = &Alds[(wave * 16 + l16) * 264 + lhi * 8];
    s16x8 a[8];
#pragma unroll
    for (int k = 0; k < 8; k++) a[k] = *(const s16x8*)(Abase + k * 32);

    f32x4 acc[8];
#pragma unroll
    for (int n = 0; n < 8; n++) acc[n] = (f32x4){0.f, 0.f, 0.f, 0.f};
#pragma unroll
    for (int n = 0; n < 8; n++) {
      const unsigned short* Bb = &Blds[(n * 16 + l16) * 264 + lhi * 8];
#pragma unroll
      for (int k = 0; k < 8; k++) {
        s16x8 b = *(const s16x8*)(Bb + k * 32);
        acc[n] = __builtin_amdgcn_mfma_f32_16x16x32_bf16(a[k], b, acc[n], 0, 0, 0);
      }
    }

#pragma unroll
    for (int n = 0; n < 8; n++) {
#pragma unroll
      for (int j = 0; j < 4; j++) {
        int gr = row0 + wave * 16 + lhi * 4 + j;
        if (gr < NN) {
          float x = acc[n][j];
          out[(size_t)gr * DD + n * 16 + l16] = x > 0.f ? x : x * SLOPE;
        }
      }
    }
  }
}

extern "C" void kernel_launch(void* const* d_in, const int* in_sizes, int n_in,
                              void* d_out, int out_size, void* d_ws, size_t ws_size,
                              hipStream_t stream) {
  const float* ent  = (const float*)d_in[0];
  const float* rel  = (const float*)d_in[1];
  const float* norm = (const float*)d_in[2];
  const float* Wr0  = (const float*)d_in[3];
  const float* Wl0  = (const float*)d_in[4];
  const float* Wr1  = (const float*)d_in[5];
  const float* Wl1  = (const float*)d_in[6];
  const int* src = (const int*)d_in[7];
  const int* dst = (const int*)d_in[8];
  const int* rid = (const int*)d_in[9];
  float* out = (float*)d_out;

  char* ws = (char*)d_ws;
  unsigned short* preb = (unsigned short*)ws;                       // 25,600,000 B
  unsigned short* Wt   = (unsigned short*)(ws + 25600000);          //    131,072 B
  int* off  = (int*)(ws + 25731072);                                //    400,004 B
  int* cur  = (int*)(ws + 26131200);                                //    400,000 B
  int* psum = (int*)(ws + 26531200);                                //        512 B
  int* deg  = (int*)(ws + 26531712);                                //    400,000 B
  int* esrc = (int*)(ws + 26931712);                                //  2,400,000 B
  int* erel = (int*)(ws + 29331712);                                //  2,400,000 B

  prep_w<<<256, 256, 0, stream>>>(Wr0, Wl0, Wr1, Wl1, Wt);

  // CSR build (once, reused by both layers)
  hipMemsetAsync(deg, 0, (size_t)NN * 4, stream);
  const int eb = (NE + 255) / 256;
  hist_deg<<<eb, 256, 0, stream>>>(dst, deg);
  scan_a<<<NB1, 256, 0, stream>>>(deg, psum);
  scan_b<<<1, 128, 0, stream>>>(psum);
  scan_c<<<NB1, 256, 0, stream>>>(deg, psum, off, cur);
  fill_csr<<<eb, 256, 0, stream>>>(src, dst, rid, cur, esrc, erel);

  const int gb = (NN * 32 + 255) / 256;

  // layer 1
  gather_csr<<<gb, 256, 0, stream>>>(ent, rel, norm, off, esrc, erel, preb);
  layer_mm<<<256, 256, 0, stream>>>(preb, ent, Wt, out);

  // layer 2 (gather reads out written by layer 1; mm rewrites out tile-locally)
  gather_csr<<<gb, 256, 0, stream>>>(out, rel, norm, off, esrc, erel, preb);
  layer_mm<<<256, 256, 0, stream>>>(preb, out, Wt + 128 * 256, out);
}